// Round 1
// 412.506 us; speedup vs baseline: 1.0695x; 1.0695x over previous
//
#include <hip/hip_runtime.h>
#include <hip/hip_bf16.h>
#include <stdint.h>

// B=128, T=256, C=768, D=768. M_total = 32768.

typedef __attribute__((ext_vector_type(8))) short short8;   // 8 x bf16 (4 VGPRs)
typedef __attribute__((ext_vector_type(4))) short short4v;  // 4 x bf16 (8B)
typedef __attribute__((ext_vector_type(4))) float f32x4;

__device__ __forceinline__ short f2bf(float f) {
    uint32_t u = __float_as_uint(f);
    u += 0x7fffu + ((u >> 16) & 1u);   // RNE
    return (short)(u >> 16);
}

// ---------------------------------------------------------------------------
__global__ __launch_bounds__(256) void cvt_x(const float* __restrict__ x,
                                             short* __restrict__ xb) {
    long i = ((long)blockIdx.x * 256 + threadIdx.x) * 4;
    f32x4 v = *(const f32x4*)(x + i);
    short4v o;
    o.x = f2bf(v.x); o.y = f2bf(v.y); o.z = f2bf(v.z); o.w = f2bf(v.w);
    *(short4v*)(xb + i) = o;
}

// W [768,768] fp32 -> Wt [768,768] bf16 transposed
__global__ __launch_bounds__(256) void cvt_wt(const float* __restrict__ W,
                                              short* __restrict__ Wt) {
    __shared__ float tile[32][33];
    int d0 = blockIdx.x * 32, c0 = blockIdx.y * 32;
    int tr = threadIdx.x >> 5, tc = threadIdx.x & 31;
    #pragma unroll
    for (int i = 0; i < 32; i += 8)
        tile[tr + i][tc] = W[(long)(c0 + tr + i) * 768 + d0 + tc];
    __syncthreads();
    #pragma unroll
    for (int i = 0; i < 32; i += 8)
        Wt[(long)(d0 + tr + i) * 768 + c0 + tc] = f2bf(tile[tc][tr + i]);
}

// RoPE table: rt[t*384 + j] = (cos, sin)
__global__ __launch_bounds__(256) void rope_tab(float2* __restrict__ rt) {
    int i = blockIdx.x * 256 + threadIdx.x;   // 98304
    int t = i / 384, j = i - t * 384;
    const float CE = -0.034603417655f;        // -2*log2(10000)/768
    float th = exp2f((float)j * CE);
    float s, c;
    sincosf((float)t * th, &s, &c);
    rt[i] = make_float2(c, s);
}

// ---------------------------------------------------------------------------
// Fused QKV GEMM: 256x256 tile, BK=64, 8 waves (2Mx4N), 8-phase schedule with
// counted vmcnt (T3+T4), setprio around MFMA clusters (T5), rotation LDS
// swizzle (0 bank conflicts, same scheme as previous kernel).
// C = A[32768x768] * B[2304x768]^T; epilogue: RoPE (q,k), transpose (v).
//
// Half-tile stream (derived, race-checked against per-phase ds_read liveness):
//   tile 2i   (buf0): B0,B1,A0,A1 staged at phases 3,4,5,6 of iter i-1
//   tile 2i+1 (buf1): B0,B1 at phases 7,8 of i-1; A0,A1 at phases 1,2 of i
//   vmcnt(4) at phase 4 confirms tile 2i+1 (2 halves = 4 loads stay in flight)
//   vmcnt(4) at phase 8 confirms tile 2i+2
//   final iteration: vmcnt(0) at phase 4 (drain), no phase-8 wait.
__global__ __launch_bounds__(512, 2)
void qkv256(const short* __restrict__ A, const short* __restrict__ B,
            short* __restrict__ Q, short* __restrict__ Kb,
            short* __restrict__ Vt, const float2* __restrict__ rt) {
    // grid 1152 flat = 8 XCDs x 16 M-stripes x 9 N-blocks (bijective: 1152%8==0)
    int p = blockIdx.x;
    int c = p & 7, j = p >> 3;          // j in [0,144)
    int st = j / 9;
    int bx = j - st * 9;                // [0,9)
    int by = c * 16 + st;               // [0,128)
    const int m0 = by * 256, n0 = bx * 256;

    __shared__ short lA[2][256 * 64];   // 64 KB
    __shared__ short lB[2][256 * 64];   // 64 KB

    const int tid = threadIdx.x;
    const int w = tid >> 6, lane = tid & 63;
    const int wm = (w >> 2) * 128;      // 2 M-waves: rows wm..wm+127
    const int wn = (w & 3) * 64;        // 4 N-waves: cols wn..wn+63
    const int lr8 = lane >> 3;
    const int scol = (((lane & 7) - lr8) & 7) * 8;  // rotation swizzle (stage)
    const int fr = lane & 15, kq = lane >> 4;

    f32x4 acc[8][4] = {};
    short8 af[4][2];    // current m-half A frags
    short8 bq[4][2];    // both n-half B frags (n0: 0-1, n1: 2-3)

#define STAGE_HALF(lX, gX, r0g, h, t) do {                                     \
    int _buf = (t) & 1;                                                        \
    _Pragma("unroll")                                                          \
    for (int _i = 0; _i < 2; ++_i) {                                           \
        int _rl = (h) * 128 + (w * 2 + _i) * 8;                                \
        const short* _g = (gX) + (long)((r0g) + _rl + lr8) * 768               \
                               + (t) * 64 + scol;                              \
        __builtin_amdgcn_global_load_lds(                                      \
            (const __attribute__((address_space(1))) void*)_g,                 \
            (__attribute__((address_space(3))) void*)(&lX[_buf][_rl * 64]),    \
            16, 0, 0);                                                         \
    }                                                                          \
} while (0)

#define LOAD_A(mh, buf) do {                                                   \
    _Pragma("unroll")                                                          \
    for (int _t = 0; _t < 4; ++_t)                                             \
        _Pragma("unroll")                                                      \
        for (int _k = 0; _k < 2; ++_k)                                         \
            af[_t][_k] = *(const short8*)(&lA[buf][                            \
                (wm + (mh) * 64 + _t * 16 + fr) * 64 +                         \
                ((_k * 4 + kq + fr) & 7) * 8]);                                \
} while (0)

#define LOAD_B(nh, buf) do {                                                   \
    _Pragma("unroll")                                                          \
    for (int _t = 0; _t < 2; ++_t)                                             \
        _Pragma("unroll")                                                      \
        for (int _k = 0; _k < 2; ++_k)                                         \
            bq[(nh) * 2 + _t][_k] = *(const short8*)(&lB[buf][                 \
                (wn + (nh) * 32 + _t * 16 + fr) * 64 +                         \
                ((_k * 4 + kq + fr) & 7) * 8]);                                \
} while (0)

#define MMA_Q(mh, nh) do {                                                     \
    __builtin_amdgcn_s_setprio(1);                                             \
    _Pragma("unroll")                                                          \
    for (int _t = 0; _t < 4; ++_t)                                             \
        _Pragma("unroll")                                                      \
        for (int _n = 0; _n < 2; ++_n)                                         \
            _Pragma("unroll")                                                  \
            for (int _k = 0; _k < 2; ++_k)                                     \
                acc[(mh) * 4 + _t][(nh) * 2 + _n] =                            \
                    __builtin_amdgcn_mfma_f32_16x16x32_bf16(                   \
                        af[_t][_k], bq[(nh) * 2 + _n][_k],                     \
                        acc[(mh) * 4 + _t][(nh) * 2 + _n], 0, 0, 0);           \
    __builtin_amdgcn_s_setprio(0);                                             \
} while (0)

#define BAR() __builtin_amdgcn_s_barrier()
#define LGKM0() asm volatile("s_waitcnt lgkmcnt(0)" ::: "memory")
#define VMC4() asm volatile("s_waitcnt vmcnt(4)" ::: "memory")
#define VMC0() asm volatile("s_waitcnt vmcnt(0)" ::: "memory")

    // prologue: T0 {B0,B1,A0,A1}, T1 {B0,B1}; confirm T0 (last 4 loads ride)
    STAGE_HALF(lB, B, n0, 0, 0);
    STAGE_HALF(lB, B, n0, 1, 0);
    STAGE_HALF(lA, A, m0, 0, 0);
    STAGE_HALF(lA, A, m0, 1, 0);
    STAGE_HALF(lB, B, n0, 0, 1);
    STAGE_HALF(lB, B, n0, 1, 1);
    VMC4();
    BAR();

    #pragma unroll 1
    for (int i = 0; i < 6; ++i) {
        const int t0 = 2 * i;
        const bool more = (i < 5);
        // phase 1: quadrant (m0,n0) of tile 2i; stage A0 of tile 2i+1 -> buf1
        LOAD_A(0, 0); LOAD_B(0, 0);
        STAGE_HALF(lA, A, m0, 0, t0 + 1);
        BAR(); LGKM0(); MMA_Q(0, 0); BAR();
        // phase 2: (m0,n1); stage A1 of 2i+1
        LOAD_B(1, 0);
        STAGE_HALF(lA, A, m0, 1, t0 + 1);
        BAR(); LGKM0(); MMA_Q(0, 1); BAR();
        // phase 3: (m1,n1); stage B0 of 2i+2 -> buf0 (B slots free after ph2)
        LOAD_A(1, 0);
        if (more) STAGE_HALF(lB, B, n0, 0, t0 + 2);
        BAR(); LGKM0(); MMA_Q(1, 1); BAR();
        // phase 4: (m1,n0) from held regs; stage B1 of 2i+2; confirm tile 2i+1
        if (more) { STAGE_HALF(lB, B, n0, 1, t0 + 2); VMC4(); }
        else      { VMC0(); }
        BAR(); LGKM0(); MMA_Q(1, 0); BAR();
        // phase 5: (m0,n0) of tile 2i+1; stage A0 of 2i+2 (A slots free after ph3)
        LOAD_A(0, 1); LOAD_B(0, 1);
        if (more) STAGE_HALF(lA, A, m0, 0, t0 + 2);
        BAR(); LGKM0(); MMA_Q(0, 0); BAR();
        // phase 6: (m0,n1); stage A1 of 2i+2
        LOAD_B(1, 1);
        if (more) STAGE_HALF(lA, A, m0, 1, t0 + 2);
        BAR(); LGKM0(); MMA_Q(0, 1); BAR();
        // phase 7: (m1,n1); stage B0 of 2i+3 -> buf1 (B slots free after ph6)
        LOAD_A(1, 1);
        if (more) STAGE_HALF(lB, B, n0, 0, t0 + 3);
        BAR(); LGKM0(); MMA_Q(1, 1); BAR();
        // phase 8: (m1,n0); stage B1 of 2i+3; confirm tile 2i+2
        if (more) { STAGE_HALF(lB, B, n0, 1, t0 + 3); VMC4(); }
        BAR(); LGKM0(); MMA_Q(1, 0); BAR();
    }

    // ---- epilogue; C/D layout: col = lane&15, row = (lane>>4)*4 + r
    const int type = (bx >= 6) ? 2 : (bx >= 3 ? 1 : 0);
    const int nl0 = n0 - type * 768;
    const int r0 = wm + (lane >> 4) * 4;
    const int c0 = wn + (lane & 15);
    if (type < 2) {
        short* dst = (type == 0) ? Q : Kb;
        const int par = lane & 1;
        #pragma unroll
        for (int tmi = 0; tmi < 8; ++tmi)
            #pragma unroll
            for (int tni = 0; tni < 4; ++tni) {
                int col = nl0 + c0 + tni * 16;
                const float2* rtc = rt + (col >> 1);
                #pragma unroll
                for (int r = 0; r < 4; ++r) {
                    int row = m0 + r0 + tmi * 16 + r;
                    float val = acc[tmi][tni][r];
                    float pv = __shfl_xor(val, 1);
                    float2 cs = rtc[(row & 255) * 384];
                    float re = par ? pv : val;
                    float im = par ? val : pv;
                    float o = par ? (re * cs.y + im * cs.x)
                                  : (re * cs.x - im * cs.y);
                    dst[(long)row * 768 + col] = f2bf(o);
                }
            }
    } else {
        #pragma unroll
        for (int tmi = 0; tmi < 8; ++tmi)
            #pragma unroll
            for (int tni = 0; tni < 4; ++tni) {
                int col = nl0 + c0 + tni * 16;
                #pragma unroll
                for (int r = 0; r < 4; ++r) {
                    int row = m0 + r0 + tmi * 16 + r;
                    Vt[((long)(row >> 8) * 768 + col) * 256 + (row & 255)] =
                        f2bf(acc[tmi][tni][r]);
                }
            }
    }
#undef STAGE_HALF
#undef LOAD_A
#undef LOAD_B
#undef MMA_Q
#undef BAR
#undef LGKM0
#undef VMC4
#undef VMC0
}

// ---------------------------------------------------------------------------
// bf16 GEMM, C = A (MxK row-major) * B^T (B is NxK row-major)
// 128x128 tile, BK=64, 4 waves (2x2), 16x16x32 MFMA, global_load_lds w=16.
// (kept for S = qk^T and out = P v)
template <int EPI, int CAUSAL, int SWZ>
__global__ __launch_bounds__(256)
void gemm_bt(const short* __restrict__ A, const short* __restrict__ B,
             void* __restrict__ C, void* __restrict__ C2, void* __restrict__ C3,
             const float2* __restrict__ rt,
             int M, int N, int K, long sA, long sB, long sC, float scale) {
    int bx, by, bz;
    if (SWZ == 2) {          // grid (2,2,128): XCD c owns 16 batches
        int p = blockIdx.x + 2 * (blockIdx.y + 2 * blockIdx.z);
        int c = p & 7, j = p >> 3;          // j in [0,64)
        bz = c * 16 + (j >> 2);
        by = (j >> 1) & 1; bx = j & 1;
    } else if (SWZ == 3) {   // grid (6,2,128): XCD c owns 16 batches
        int p = blockIdx.x + 6 * (blockIdx.y + 2 * blockIdx.z);
        int c = p & 7, j = p >> 3;          // j in [0,192)
        int bt = j / 12;
        bz = c * 16 + bt;
        int t = j - bt * 12;
        by = t / 6; bx = t - (t / 6) * 6;
    } else {
        bx = blockIdx.x; by = blockIdx.y; bz = blockIdx.z;
    }
    const int m0 = by * 128;
    const int n0 = bx * 128;
    if (CAUSAL == 1 && n0 > m0) return;

    __shared__ short lA[128 * 64];
    __shared__ short lB[128 * 64];
    const short* Ab = A + (long)bz * sA;
    const short* Bb = B + (long)bz * sB;
    const int tid = threadIdx.x;
    const int w = tid >> 6, lane = tid & 63;
    const int wm = (w >> 1) * 64;
    const int wn = (w & 1) * 64;
    const int lrow8 = lane >> 3;
    const int lcol = (((lane & 7) - lrow8) & 7) * 8;
    const int fr = lane & 15;
    const int kq = lane >> 4;

    const int Kend = (CAUSAL == 2) ? (m0 + 128 < K ? m0 + 128 : K) : K;

    f32x4 acc[4][4] = {};

    for (int k0 = 0; k0 < Kend; k0 += 64) {
        #pragma unroll
        for (int i = 0; i < 4; ++i) {
            int seg = i * 4 + w;
            int row = seg * 8 + lrow8;
            const short* ga = Ab + (long)(m0 + row) * K + k0 + lcol;
            __builtin_amdgcn_global_load_lds(
                (const __attribute__((address_space(1))) void*)ga,
                (__attribute__((address_space(3))) void*)(lA + seg * 512),
                16, 0, 0);
            const short* gb = Bb + (long)(n0 + row) * K + k0 + lcol;
            __builtin_amdgcn_global_load_lds(
                (const __attribute__((address_space(1))) void*)gb,
                (__attribute__((address_space(3))) void*)(lB + seg * 512),
                16, 0, 0);
        }
        __syncthreads();

        #pragma unroll
        for (int c = 0; c < 2; ++c) {
            const int sphys = ((c * 4 + kq + fr) & 7) * 8;
            short8 afr[4], bfr[4];
            #pragma unroll
            for (int tmi = 0; tmi < 4; ++tmi)
                afr[tmi] = *(const short8*)(lA + (wm + fr + tmi * 16) * 64 + sphys);
            #pragma unroll
            for (int tni = 0; tni < 4; ++tni)
                bfr[tni] = *(const short8*)(lB + (wn + fr + tni * 16) * 64 + sphys);
            #pragma unroll
            for (int tmi = 0; tmi < 4; ++tmi)
                #pragma unroll
                for (int tni = 0; tni < 4; ++tni)
                    acc[tmi][tni] = __builtin_amdgcn_mfma_f32_16x16x32_bf16(
                        afr[tmi], bfr[tni], acc[tmi][tni], 0, 0, 0);
        }
        __syncthreads();
    }

    // ---- epilogue; C/D layout: col = lane&15, row = (lane>>4)*4 + r
    const int r0 = wm + (lane >> 4) * 4;
    const int c0 = wn + (lane & 15);

    if (EPI == 2) {
        #pragma unroll
        for (int tmi = 0; tmi < 4; ++tmi)
            #pragma unroll
            for (int tni = 0; tni < 4; ++tni)
                #pragma unroll
                for (int r = 0; r < 4; ++r) {
                    int row = m0 + r0 + tmi * 16 + r;
                    int col = n0 + c0 + tni * 16;
                    ((float*)C)[(long)bz * sC + (long)row * N + col] =
                        acc[tmi][tni][r] * scale;
                }
    }
}

// ---------------------------------------------------------------------------
// Causal softmax: one wave per row of S [32768 x 256]; P bf16 out.
__global__ __launch_bounds__(256) void softmax_p(const float* __restrict__ S,
                                                 short* __restrict__ P) {
    int wv = threadIdx.x >> 6, lane = threadIdx.x & 63;
    int row = blockIdx.x * 4 + wv;
    int t = row & 255;
    f32x4 v = *(const f32x4*)(S + (long)row * 256 + lane * 4);
    float vals[4];
    float m = -1e30f;
    #pragma unroll
    for (int j = 0; j < 4; ++j) {
        int n = lane * 4 + j;
        vals[j] = (n <= t) ? v[j] : -1e30f;
        m = fmaxf(m, vals[j]);
    }
    #pragma unroll
    for (int o = 32; o; o >>= 1) m = fmaxf(m, __shfl_xor(m, o));
    float e[4], sum = 0.f;
    #pragma unroll
    for (int j = 0; j < 4; ++j) { e[j] = __expf(vals[j] - m); sum += e[j]; }
    #pragma unroll
    for (int o = 32; o; o >>= 1) sum += __shfl_xor(sum, o);
    float inv = 1.0f / sum;
    short4v o4;
    o4.x = f2bf(e[0] * inv); o4.y = f2bf(e[1] * inv);
    o4.z = f2bf(e[2] * inv); o4.w = f2bf(e[3] * inv);
    *(short4v*)(P + (long)row * 256 + lane * 4) = o4;
}

// ---------------------------------------------------------------------------
extern "C" void kernel_launch(void* const* d_in, const int* in_sizes, int n_in,
                              void* d_out, int out_size, void* d_ws, size_t ws_size,
                              hipStream_t stream) {
    const float* x  = (const float*)d_in[0];
    const float* Wq = (const float*)d_in[1];
    const float* Wk = (const float*)d_in[2];
    const float* Wv = (const float*)d_in[3];

    char* ws = (char*)d_ws;
    short*  xb = (short*)(ws);                   // 48 MB   x bf16
    short*  wt = (short*)(ws + 50331648);        // 3.375MB Wqkv^T bf16 [2304,768]
    short*  qb = (short*)(ws + 53870592);        // 48 MB   q bf16 (roped)
    short*  kb = (short*)(ws + 104202240);       // 48 MB   k bf16 (roped)
    short*  vt = (short*)(ws + 154533888);       // 48 MB   v^T bf16 [128][768][256]
    float*  S  = (float*)(ws + 204865536);       // 32 MB   scores fp32
    short*  P  = (short*)(ws + 238419968);       // 16 MB   probs bf16
    float2* rt = (float2*)(ws + 255197184);      // 768 KB  rope table

    cvt_x<<<24576, 256, 0, stream>>>(x, xb);
    dim3 gw(24, 24);
    cvt_wt<<<gw, 256, 0, stream>>>(Wq, wt);
    cvt_wt<<<gw, 256, 0, stream>>>(Wk, wt + 589824);
    cvt_wt<<<gw, 256, 0, stream>>>(Wv, wt + 1179648);
    rope_tab<<<384, 256, 0, stream>>>(rt);

    // Fused QKV: [32768,768] x [2304,768]^T, 256^2 8-phase, RoPE/v-T epilogue
    qkv256<<<1152, 512, 0, stream>>>(xb, wt, qb, kb, vt, rt);

    // S = q k^T * scale (batched); upper tiles skipped
    dim3 g2(2, 2, 128);
    gemm_bt<2, 1, 2><<<g2, 256, 0, stream>>>(qb, kb, S, nullptr, nullptr, nullptr,
                                             256, 256, 768, 196608, 196608, 65536,
                                             0.0360843918f);

    softmax_p<<<8192, 256, 0, stream>>>(S, P);

    // out = P v (batched); K limited to causal extent
    dim3 g3(6, 2, 128);
    gemm_bt<2, 2, 3><<<g3, 256, 0, stream>>>(P, vt, (float*)d_out, nullptr,
                                             nullptr, nullptr, 256, 768, 256,
                                             65536, 196608, 196608, 1.0f);
}

// Round 2
// 412.071 us; speedup vs baseline: 1.0706x; 1.0011x over previous
//
#include <hip/hip_runtime.h>
#include <hip/hip_bf16.h>
#include <stdint.h>

// B=128, T=256, C=768, D=768. M_total = 32768.

typedef __attribute__((ext_vector_type(8))) short short8;   // 8 x bf16 (4 VGPRs)
typedef __attribute__((ext_vector_type(4))) short short4v;  // 4 x bf16 (8B)
typedef __attribute__((ext_vector_type(4))) float f32x4;

__device__ __forceinline__ short f2bf(float f) {
    uint32_t u = __float_as_uint(f);
    u += 0x7fffu + ((u >> 16) & 1u);   // RNE
    return (short)(u >> 16);
}

// ---------------------------------------------------------------------------
__global__ __launch_bounds__(256) void cvt_x(const float* __restrict__ x,
                                             short* __restrict__ xb) {
    long i = ((long)blockIdx.x * 256 + threadIdx.x) * 4;
    f32x4 v = *(const f32x4*)(x + i);
    short4v o;
    o.x = f2bf(v.x); o.y = f2bf(v.y); o.z = f2bf(v.z); o.w = f2bf(v.w);
    *(short4v*)(xb + i) = o;
}

// W [768,768] fp32 -> Wt [768,768] bf16 transposed
__global__ __launch_bounds__(256) void cvt_wt(const float* __restrict__ W,
                                              short* __restrict__ Wt) {
    __shared__ float tile[32][33];
    int d0 = blockIdx.x * 32, c0 = blockIdx.y * 32;
    int tr = threadIdx.x >> 5, tc = threadIdx.x & 31;
    #pragma unroll
    for (int i = 0; i < 32; i += 8)
        tile[tr + i][tc] = W[(long)(c0 + tr + i) * 768 + d0 + tc];
    __syncthreads();
    #pragma unroll
    for (int i = 0; i < 32; i += 8)
        Wt[(long)(d0 + tr + i) * 768 + c0 + tc] = f2bf(tile[tc][tr + i]);
}

// RoPE table: rt[t*384 + j] = (cos, sin)
__global__ __launch_bounds__(256) void rope_tab(float2* __restrict__ rt) {
    int i = blockIdx.x * 256 + threadIdx.x;   // 98304
    int t = i / 384, j = i - t * 384;
    const float CE = -0.034603417655f;        // -2*log2(10000)/768
    float th = exp2f((float)j * CE);
    float s, c;
    sincosf((float)t * th, &s, &c);
    rt[i] = make_float2(c, s);
}

// ---------------------------------------------------------------------------
// Fused QKV GEMM: 256x256 tile, BK=64, 8 waves (2Mx4N), 8-phase schedule with
// counted vmcnt (T3+T4), setprio around MFMA clusters (T5), rotation LDS
// swizzle (0 bank conflicts).
// C = A[32768x768] * B[2304x768]^T; epilogue: RoPE (q,k), transpose (v).
// vmcnt moved AFTER the MFMA cluster in phases 4/8 (guarantee only needs to
// hold before the following barrier; lets matrix pipe fill during HBM wait).
__global__ __launch_bounds__(512, 2)
void qkv256(const short* __restrict__ A, const short* __restrict__ B,
            short* __restrict__ Q, short* __restrict__ Kb,
            short* __restrict__ Vt, const float2* __restrict__ rt) {
    // grid 1152 flat = 8 XCDs x 16 M-stripes x 9 N-blocks (bijective)
    int p = blockIdx.x;
    int c = p & 7, j = p >> 3;          // j in [0,144)
    int st = j / 9;
    int bx = j - st * 9;                // [0,9)
    int by = c * 16 + st;               // [0,128)
    const int m0 = by * 256, n0 = bx * 256;

    __shared__ short lA[2][256 * 64];   // 64 KB
    __shared__ short lB[2][256 * 64];   // 64 KB

    const int tid = threadIdx.x;
    const int w = tid >> 6, lane = tid & 63;
    const int wm = (w >> 2) * 128;      // 2 M-waves
    const int wn = (w & 3) * 64;        // 4 N-waves
    const int lr8 = lane >> 3;
    const int scol = (((lane & 7) - lr8) & 7) * 8;  // rotation swizzle (stage)
    const int fr = lane & 15, kq = lane >> 4;

    f32x4 acc[8][4] = {};
    short8 af[4][2];
    short8 bq[4][2];

#define STAGE_HALF(lX, gX, r0g, h, t) do {                                     \
    int _buf = (t) & 1;                                                        \
    _Pragma("unroll")                                                          \
    for (int _i = 0; _i < 2; ++_i) {                                           \
        int _rl = (h) * 128 + (w * 2 + _i) * 8;                                \
        const short* _g = (gX) + (long)((r0g) + _rl + lr8) * 768               \
                               + (t) * 64 + scol;                              \
        __builtin_amdgcn_global_load_lds(                                      \
            (const __attribute__((address_space(1))) void*)_g,                 \
            (__attribute__((address_space(3))) void*)(&lX[_buf][_rl * 64]),    \
            16, 0, 0);                                                         \
    }                                                                          \
} while (0)

#define LOAD_A(mh, buf) do {                                                   \
    _Pragma("unroll")                                                          \
    for (int _t = 0; _t < 4; ++_t)                                             \
        _Pragma("unroll")                                                      \
        for (int _k = 0; _k < 2; ++_k)                                         \
            af[_t][_k] = *(const short8*)(&lA[buf][                            \
                (wm + (mh) * 64 + _t * 16 + fr) * 64 +                         \
                ((_k * 4 + kq + fr) & 7) * 8]);                                \
} while (0)

#define LOAD_B(nh, buf) do {                                                   \
    _Pragma("unroll")                                                          \
    for (int _t = 0; _t < 2; ++_t)                                             \
        _Pragma("unroll")                                                      \
        for (int _k = 0; _k < 2; ++_k)                                         \
            bq[(nh) * 2 + _t][_k] = *(const short8*)(&lB[buf][                 \
                (wn + (nh) * 32 + _t * 16 + fr) * 64 +                         \
                ((_k * 4 + kq + fr) & 7) * 8]);                                \
} while (0)

#define MMA_Q(mh, nh) do {                                                     \
    __builtin_amdgcn_s_setprio(1);                                             \
    _Pragma("unroll")                                                          \
    for (int _t = 0; _t < 4; ++_t)                                             \
        _Pragma("unroll")                                                      \
        for (int _n = 0; _n < 2; ++_n)                                         \
            _Pragma("unroll")                                                  \
            for (int _k = 0; _k < 2; ++_k)                                     \
                acc[(mh) * 4 + _t][(nh) * 2 + _n] =                            \
                    __builtin_amdgcn_mfma_f32_16x16x32_bf16(                   \
                        af[_t][_k], bq[(nh) * 2 + _n][_k],                     \
                        acc[(mh) * 4 + _t][(nh) * 2 + _n], 0, 0, 0);           \
    __builtin_amdgcn_s_setprio(0);                                             \
} while (0)

#define BAR() __builtin_amdgcn_s_barrier()
#define LGKM0() asm volatile("s_waitcnt lgkmcnt(0)" ::: "memory")
#define VMC4() asm volatile("s_waitcnt vmcnt(4)" ::: "memory")
#define VMC0() asm volatile("s_waitcnt vmcnt(0)" ::: "memory")

    // prologue: T0 {B0,B1,A0,A1}, T1 {B0,B1}; confirm T0
    STAGE_HALF(lB, B, n0, 0, 0);
    STAGE_HALF(lB, B, n0, 1, 0);
    STAGE_HALF(lA, A, m0, 0, 0);
    STAGE_HALF(lA, A, m0, 1, 0);
    STAGE_HALF(lB, B, n0, 0, 1);
    STAGE_HALF(lB, B, n0, 1, 1);
    VMC4();
    BAR();

    #pragma unroll 1
    for (int i = 0; i < 6; ++i) {
        const int t0 = 2 * i;
        const bool more = (i < 5);
        // phase 1
        LOAD_A(0, 0); LOAD_B(0, 0);
        STAGE_HALF(lA, A, m0, 0, t0 + 1);
        BAR(); LGKM0(); MMA_Q(0, 0); BAR();
        // phase 2
        LOAD_B(1, 0);
        STAGE_HALF(lA, A, m0, 1, t0 + 1);
        BAR(); LGKM0(); MMA_Q(0, 1); BAR();
        // phase 3
        LOAD_A(1, 0);
        if (more) STAGE_HALF(lB, B, n0, 0, t0 + 2);
        BAR(); LGKM0(); MMA_Q(1, 1); BAR();
        // phase 4: held regs; confirm tile 2i+1 after MFMA
        if (more) STAGE_HALF(lB, B, n0, 1, t0 + 2);
        BAR(); LGKM0(); MMA_Q(1, 0);
        if (more) { VMC4(); } else { VMC0(); }
        BAR();
        // phase 5
        LOAD_A(0, 1); LOAD_B(0, 1);
        if (more) STAGE_HALF(lA, A, m0, 0, t0 + 2);
        BAR(); LGKM0(); MMA_Q(0, 0); BAR();
        // phase 6
        LOAD_B(1, 1);
        if (more) STAGE_HALF(lA, A, m0, 1, t0 + 2);
        BAR(); LGKM0(); MMA_Q(0, 1); BAR();
        // phase 7
        LOAD_A(1, 1);
        if (more) STAGE_HALF(lB, B, n0, 0, t0 + 3);
        BAR(); LGKM0(); MMA_Q(1, 1); BAR();
        // phase 8: confirm tile 2i+2 after MFMA
        if (more) STAGE_HALF(lB, B, n0, 1, t0 + 3);
        BAR(); LGKM0(); MMA_Q(1, 0);
        if (more) VMC4();
        BAR();
    }

    // ---- epilogue; C/D layout: col = lane&15, row = (lane>>4)*4 + r
    const int type = (bx >= 6) ? 2 : (bx >= 3 ? 1 : 0);
    const int nl0 = n0 - type * 768;
    const int r0 = wm + (lane >> 4) * 4;
    const int c0 = wn + (lane & 15);
    if (type < 2) {
        short* dst = (type == 0) ? Q : Kb;
        const int par = lane & 1;
        #pragma unroll
        for (int tmi = 0; tmi < 8; ++tmi)
            #pragma unroll
            for (int tni = 0; tni < 4; ++tni) {
                int col = nl0 + c0 + tni * 16;
                const float2* rtc = rt + (col >> 1);
                #pragma unroll
                for (int r = 0; r < 4; ++r) {
                    int row = m0 + r0 + tmi * 16 + r;
                    float val = acc[tmi][tni][r];
                    float pv = __shfl_xor(val, 1);
                    float2 cs = rtc[(row & 255) * 384];
                    float re = par ? pv : val;
                    float im = par ? val : pv;
                    float o = par ? (re * cs.y + im * cs.x)
                                  : (re * cs.x - im * cs.y);
                    dst[(long)row * 768 + col] = f2bf(o);
                }
            }
    } else {
        #pragma unroll
        for (int tmi = 0; tmi < 8; ++tmi)
            #pragma unroll
            for (int tni = 0; tni < 4; ++tni) {
                int col = nl0 + c0 + tni * 16;
                #pragma unroll
                for (int r = 0; r < 4; ++r) {
                    int row = m0 + r0 + tmi * 16 + r;
                    Vt[((long)(row >> 8) * 768 + col) * 256 + (row & 255)] =
                        f2bf(acc[tmi][tni][r]);
                }
            }
    }
#undef STAGE_HALF
#undef LOAD_A
#undef LOAD_B
#undef MMA_Q
#undef BAR
#undef LGKM0
#undef VMC4
#undef VMC0
}

// ---------------------------------------------------------------------------
// Fused S = q k^T * scale -> causal softmax -> P bf16, one kernel.
// grid 256 flat (1 block/CU, XCD-swizzled: batch pairs stay on one XCD so the
// two m-halves share the k-batch via L2). 512 threads = 8 waves (2m x 4n).
// Block: rows [mh*128, +128) of batch bz, all 256 k-cols, K=768 (12 steps,
// single-buffer 2-barrier: aggregate fetch-bound, 48KB LDS/step).
// Softmax: mask+scale in-reg, row-max/sum via shfl over the 16 lanes sharing
// a row, then cross-wave (4 n-waves) exchange through 4KB of LDS scratch.
__global__ __launch_bounds__(512)
void s_softmax(const short* __restrict__ Qm, const short* __restrict__ Km,
               short* __restrict__ P, float scale) {
    int p = blockIdx.x;
    int c = p & 7, j = p >> 3;          // j in [0,32)
    int bz = c * 16 + (j >> 1);
    int mh = j & 1;
    const short* Ab = Qm + (long)bz * 196608 + (long)mh * 98304;  // 128*768
    const short* Bb = Km + (long)bz * 196608;

    __shared__ short lA[128 * 64];      // 16 KB
    __shared__ short lB[256 * 64];      // 32 KB

    const int tid = threadIdx.x;
    const int w = tid >> 6, lane = tid & 63;
    const int wm = (w >> 2) * 64;       // 2 m-groups
    const int wn = (w & 3) * 64;        // 4 n-groups
    const int lr8 = lane >> 3;
    const int scol = (((lane & 7) - lr8) & 7) * 8;
    const int fr = lane & 15, kq = lane >> 4;

    f32x4 acc[4][4] = {};

    for (int k0 = 0; k0 < 768; k0 += 64) {
        #pragma unroll
        for (int i = 0; i < 2; ++i) {
            int seg = i * 8 + w;                 // 16 A-segs of 8 rows
            const short* ga = Ab + (long)(seg * 8 + lr8) * 768 + k0 + scol;
            __builtin_amdgcn_global_load_lds(
                (const __attribute__((address_space(1))) void*)ga,
                (__attribute__((address_space(3))) void*)(lA + seg * 512),
                16, 0, 0);
        }
        #pragma unroll
        for (int i = 0; i < 4; ++i) {
            int seg = i * 8 + w;                 // 32 B-segs of 8 rows
            const short* gb = Bb + (long)(seg * 8 + lr8) * 768 + k0 + scol;
            __builtin_amdgcn_global_load_lds(
                (const __attribute__((address_space(1))) void*)gb,
                (__attribute__((address_space(3))) void*)(lB + seg * 512),
                16, 0, 0);
        }
        __syncthreads();
        #pragma unroll
        for (int cc = 0; cc < 2; ++cc) {
            const int sphys = ((cc * 4 + kq + fr) & 7) * 8;
            short8 afr[4], bfr[4];
            #pragma unroll
            for (int tmi = 0; tmi < 4; ++tmi)
                afr[tmi] = *(const short8*)(lA + (wm + fr + tmi * 16) * 64 + sphys);
            #pragma unroll
            for (int tni = 0; tni < 4; ++tni)
                bfr[tni] = *(const short8*)(lB + (wn + fr + tni * 16) * 64 + sphys);
            #pragma unroll
            for (int tmi = 0; tmi < 4; ++tmi)
                #pragma unroll
                for (int tni = 0; tni < 4; ++tni)
                    acc[tmi][tni] = __builtin_amdgcn_mfma_f32_16x16x32_bf16(
                        afr[tmi], bfr[tni], acc[tmi][tni], 0, 0, 0);
        }
        __syncthreads();
    }

    // ---- fused causal softmax -----------------------------------------
    // C/D layout: col = wn + (lane&15) + tni*16, rowLocal = wm + tmi*16 +
    // (lane>>4)*4 + r  (rowLocal in [0,128); global q-row = bz*256+mh*128+rowLocal)
    const int r0 = (lane >> 4) * 4;
    const int cb = lane & 15;
    const int nw = w & 3;
    float* redm = (float*)lA;            // [128][4] row-max partials (2KB)
    float* reds = redm + 512;            // [128][4] row-sum partials (2KB)

    float M[16];
    // 1) mask + scale, wave-local row max (over this wave's 64 cols)
    #pragma unroll
    for (int tmi = 0; tmi < 4; ++tmi)
        #pragma unroll
        for (int r = 0; r < 4; ++r) {
            int rowL = wm + tmi * 16 + r0 + r;
            int tloc = mh * 128 + rowL;
            float m = -1e30f;
            #pragma unroll
            for (int tni = 0; tni < 4; ++tni) {
                int col = wn + cb + tni * 16;
                float v = (col <= tloc) ? acc[tmi][tni][r] * scale : -1e30f;
                acc[tmi][tni][r] = v;
                m = fmaxf(m, v);
            }
            m = fmaxf(m, __shfl_xor(m, 1));
            m = fmaxf(m, __shfl_xor(m, 2));
            m = fmaxf(m, __shfl_xor(m, 4));
            m = fmaxf(m, __shfl_xor(m, 8));
            M[tmi * 4 + r] = m;
        }
    // 2) cross-wave max via LDS (lane&15==0 lanes hold distinct rows)
    if (cb == 0) {
        #pragma unroll
        for (int tmi = 0; tmi < 4; ++tmi)
            #pragma unroll
            for (int r = 0; r < 4; ++r)
                redm[(wm + tmi * 16 + r0 + r) * 4 + nw] = M[tmi * 4 + r];
    }
    __syncthreads();
    #pragma unroll
    for (int tmi = 0; tmi < 4; ++tmi)
        #pragma unroll
        for (int r = 0; r < 4; ++r) {
            f32x4 v = *(const f32x4*)(redm + (wm + tmi * 16 + r0 + r) * 4);
            M[tmi * 4 + r] = fmaxf(fmaxf(v.x, v.y), fmaxf(v.z, v.w));
        }
    // 3) exp + wave-local row sum
    float Sm[16];
    #pragma unroll
    for (int tmi = 0; tmi < 4; ++tmi)
        #pragma unroll
        for (int r = 0; r < 4; ++r) {
            float mm = M[tmi * 4 + r];
            float s = 0.f;
            #pragma unroll
            for (int tni = 0; tni < 4; ++tni) {
                float e = __expf(acc[tmi][tni][r] - mm);
                acc[tmi][tni][r] = e;
                s += e;
            }
            s += __shfl_xor(s, 1);
            s += __shfl_xor(s, 2);
            s += __shfl_xor(s, 4);
            s += __shfl_xor(s, 8);
            Sm[tmi * 4 + r] = s;
        }
    if (cb == 0) {
        #pragma unroll
        for (int tmi = 0; tmi < 4; ++tmi)
            #pragma unroll
            for (int r = 0; r < 4; ++r)
                reds[(wm + tmi * 16 + r0 + r) * 4 + nw] = Sm[tmi * 4 + r];
    }
    __syncthreads();
    // 4) normalize + store P bf16
    const long rowBase = (long)bz * 256 + mh * 128;
    #pragma unroll
    for (int tmi = 0; tmi < 4; ++tmi)
        #pragma unroll
        for (int r = 0; r < 4; ++r) {
            int rowL = wm + tmi * 16 + r0 + r;
            f32x4 v = *(const f32x4*)(reds + rowL * 4);
            float inv = 1.0f / (v.x + v.y + v.z + v.w);
            short* pr = P + (rowBase + rowL) * 256;
            #pragma unroll
            for (int tni = 0; tni < 4; ++tni)
                pr[wn + cb + tni * 16] = f2bf(acc[tmi][tni][r] * inv);
        }
}

// ---------------------------------------------------------------------------
// bf16 GEMM, C = A (MxK row-major) * B^T (B is NxK row-major)
// 128x128 tile, BK=64, 4 waves (2x2), 16x16x32 MFMA. (kept for out = P v)
template <int EPI, int CAUSAL, int SWZ>
__global__ __launch_bounds__(256)
void gemm_bt(const short* __restrict__ A, const short* __restrict__ B,
             void* __restrict__ C, void* __restrict__ C2, void* __restrict__ C3,
             const float2* __restrict__ rt,
             int M, int N, int K, long sA, long sB, long sC, float scale) {
    int bx, by, bz;
    if (SWZ == 3) {          // grid (6,2,128): XCD c owns 16 batches
        int p = blockIdx.x + 6 * (blockIdx.y + 2 * blockIdx.z);
        int c = p & 7, j = p >> 3;          // j in [0,192)
        int bt = j / 12;
        bz = c * 16 + bt;
        int t = j - bt * 12;
        by = t / 6; bx = t - (t / 6) * 6;
    } else {
        bx = blockIdx.x; by = blockIdx.y; bz = blockIdx.z;
    }
    const int m0 = by * 128;
    const int n0 = bx * 128;
    if (CAUSAL == 1 && n0 > m0) return;

    __shared__ short lA[128 * 64];
    __shared__ short lB[128 * 64];
    const short* Ab = A + (long)bz * sA;
    const short* Bb = B + (long)bz * sB;
    const int tid = threadIdx.x;
    const int w = tid >> 6, lane = tid & 63;
    const int wm = (w >> 1) * 64;
    const int wn = (w & 1) * 64;
    const int lrow8 = lane >> 3;
    const int lcol = (((lane & 7) - lrow8) & 7) * 8;
    const int fr = lane & 15;
    const int kq = lane >> 4;

    const int Kend = (CAUSAL == 2) ? (m0 + 128 < K ? m0 + 128 : K) : K;

    f32x4 acc[4][4] = {};

    for (int k0 = 0; k0 < Kend; k0 += 64) {
        #pragma unroll
        for (int i = 0; i < 4; ++i) {
            int seg = i * 4 + w;
            int row = seg * 8 + lrow8;
            const short* ga = Ab + (long)(m0 + row) * K + k0 + lcol;
            __builtin_amdgcn_global_load_lds(
                (const __attribute__((address_space(1))) void*)ga,
                (__attribute__((address_space(3))) void*)(lA + seg * 512),
                16, 0, 0);
            const short* gb = Bb + (long)(n0 + row) * K + k0 + lcol;
            __builtin_amdgcn_global_load_lds(
                (const __attribute__((address_space(1))) void*)gb,
                (__attribute__((address_space(3))) void*)(lB + seg * 512),
                16, 0, 0);
        }
        __syncthreads();

        #pragma unroll
        for (int c = 0; c < 2; ++c) {
            const int sphys = ((c * 4 + kq + fr) & 7) * 8;
            short8 afr[4], bfr[4];
            #pragma unroll
            for (int tmi = 0; tmi < 4; ++tmi)
                afr[tmi] = *(const short8*)(lA + (wm + fr + tmi * 16) * 64 + sphys);
            #pragma unroll
            for (int tni = 0; tni < 4; ++tni)
                bfr[tni] = *(const short8*)(lB + (wn + fr + tni * 16) * 64 + sphys);
            #pragma unroll
            for (int tmi = 0; tmi < 4; ++tmi)
                #pragma unroll
                for (int tni = 0; tni < 4; ++tni)
                    acc[tmi][tni] = __builtin_amdgcn_mfma_f32_16x16x32_bf16(
                        afr[tmi], bfr[tni], acc[tmi][tni], 0, 0, 0);
        }
        __syncthreads();
    }

    // ---- epilogue; C/D layout: col = lane&15, row = (lane>>4)*4 + r
    const int r0 = wm + (lane >> 4) * 4;
    const int c0 = wn + (lane & 15);

    if (EPI == 2) {
        #pragma unroll
        for (int tmi = 0; tmi < 4; ++tmi)
            #pragma unroll
            for (int tni = 0; tni < 4; ++tni)
                #pragma unroll
                for (int r = 0; r < 4; ++r) {
                    int row = m0 + r0 + tmi * 16 + r;
                    int col = n0 + c0 + tni * 16;
                    ((float*)C)[(long)bz * sC + (long)row * N + col] =
                        acc[tmi][tni][r] * scale;
                }
    }
}

// ---------------------------------------------------------------------------
extern "C" void kernel_launch(void* const* d_in, const int* in_sizes, int n_in,
                              void* d_out, int out_size, void* d_ws, size_t ws_size,
                              hipStream_t stream) {
    const float* x  = (const float*)d_in[0];
    const float* Wq = (const float*)d_in[1];
    const float* Wk = (const float*)d_in[2];
    const float* Wv = (const float*)d_in[3];

    char* ws = (char*)d_ws;
    short*  xb = (short*)(ws);                   // 48 MB   x bf16
    short*  wt = (short*)(ws + 50331648);        // 3.375MB Wqkv^T bf16 [2304,768]
    short*  qb = (short*)(ws + 53870592);        // 48 MB   q bf16 (roped)
    short*  kb = (short*)(ws + 104202240);       // 48 MB   k bf16 (roped)
    short*  vt = (short*)(ws + 154533888);       // 48 MB   v^T bf16 [128][768][256]
    short*  P  = (short*)(ws + 238419968);       // 16 MB   probs bf16
    float2* rt = (float2*)(ws + 255197184);      // 768 KB  rope table

    cvt_x<<<24576, 256, 0, stream>>>(x, xb);
    dim3 gw(24, 24);
    cvt_wt<<<gw, 256, 0, stream>>>(Wq, wt);
    cvt_wt<<<gw, 256, 0, stream>>>(Wk, wt + 589824);
    cvt_wt<<<gw, 256, 0, stream>>>(Wv, wt + 1179648);
    rope_tab<<<384, 256, 0, stream>>>(rt);

    // Fused QKV: [32768,768] x [2304,768]^T, 256^2 8-phase, RoPE/v-T epilogue
    qkv256<<<1152, 512, 0, stream>>>(xb, wt, qb, kb, vt, rt);

    // Fused S = q k^T * scale -> causal softmax -> P (bf16)
    s_softmax<<<256, 512, 0, stream>>>(qb, kb, P, 0.0360843918f);

    // out = P v (batched); K limited to causal extent
    dim3 g3(6, 2, 128);
    gemm_bt<2, 2, 3><<<g3, 256, 0, stream>>>(P, vt, (float*)d_out, nullptr,
                                             nullptr, nullptr, 256, 768, 256,
                                             65536, 196608, 196608, 1.0f);
}

// Round 3
// 389.651 us; speedup vs baseline: 1.1322x; 1.0575x over previous
//
#include <hip/hip_runtime.h>
#include <hip/hip_bf16.h>
#include <stdint.h>

// B=128, T=256, C=768, D=768. M_total = 32768.

typedef __attribute__((ext_vector_type(8))) short short8;   // 8 x bf16 (4 VGPRs)
typedef __attribute__((ext_vector_type(4))) short short4v;  // 4 x bf16 (8B)
typedef __attribute__((ext_vector_type(4))) float f32x4;

__device__ __forceinline__ short f2bf(float f) {
    uint32_t u = __float_as_uint(f);
    u += 0x7fffu + ((u >> 16) & 1u);   // RNE
    return (short)(u >> 16);
}

// ---------------------------------------------------------------------------
__global__ __launch_bounds__(256) void cvt_x(const float* __restrict__ x,
                                             short* __restrict__ xb) {
    long i = ((long)blockIdx.x * 256 + threadIdx.x) * 4;
    f32x4 v = *(const f32x4*)(x + i);
    short4v o;
    o.x = f2bf(v.x); o.y = f2bf(v.y); o.z = f2bf(v.z); o.w = f2bf(v.w);
    *(short4v*)(xb + i) = o;
}

// W [768,768] fp32 -> Wt [768,768] bf16 transposed
__global__ __launch_bounds__(256) void cvt_wt(const float* __restrict__ W,
                                              short* __restrict__ Wt) {
    __shared__ float tile[32][33];
    int d0 = blockIdx.x * 32, c0 = blockIdx.y * 32;
    int tr = threadIdx.x >> 5, tc = threadIdx.x & 31;
    #pragma unroll
    for (int i = 0; i < 32; i += 8)
        tile[tr + i][tc] = W[(long)(c0 + tr + i) * 768 + d0 + tc];
    __syncthreads();
    #pragma unroll
    for (int i = 0; i < 32; i += 8)
        Wt[(long)(d0 + tr + i) * 768 + c0 + tc] = f2bf(tile[tc][tr + i]);
}

// RoPE table: rt[t*384 + j] = (cos, sin)
__global__ __launch_bounds__(256) void rope_tab(float2* __restrict__ rt) {
    int i = blockIdx.x * 256 + threadIdx.x;   // 98304
    int t = i / 384, j = i - t * 384;
    const float CE = -0.034603417655f;        // -2*log2(10000)/768
    float th = exp2f((float)j * CE);
    float s, c;
    sincosf((float)t * th, &s, &c);
    rt[i] = make_float2(c, s);
}

// ---------------------------------------------------------------------------
// Fused QKV GEMM: 256x256 tile, BK=64, 8 waves (2Mx4N), 8-phase schedule with
// counted vmcnt (T3+T4), setprio around MFMA clusters (T5), rotation LDS
// swizzle (0 bank conflicts).
// C = A[32768x768] * B[2304x768]^T; epilogue: RoPE (q,k), transpose (v).
__global__ __launch_bounds__(512, 2)
void qkv256(const short* __restrict__ A, const short* __restrict__ B,
            short* __restrict__ Q, short* __restrict__ Kb,
            short* __restrict__ Vt, const float2* __restrict__ rt) {
    // grid 1152 flat = 8 XCDs x 16 M-stripes x 9 N-blocks (bijective)
    int p = blockIdx.x;
    int c = p & 7, j = p >> 3;          // j in [0,144)
    int st = j / 9;
    int bx = j - st * 9;                // [0,9)
    int by = c * 16 + st;               // [0,128)
    const int m0 = by * 256, n0 = bx * 256;

    __shared__ short lA[2][256 * 64];   // 64 KB
    __shared__ short lB[2][256 * 64];   // 64 KB

    const int tid = threadIdx.x;
    const int w = tid >> 6, lane = tid & 63;
    const int wm = (w >> 2) * 128;      // 2 M-waves
    const int wn = (w & 3) * 64;        // 4 N-waves
    const int lr8 = lane >> 3;
    const int scol = (((lane & 7) - lr8) & 7) * 8;  // rotation swizzle (stage)
    const int fr = lane & 15, kq = lane >> 4;

    f32x4 acc[8][4] = {};
    short8 af[4][2];
    short8 bq[4][2];

#define STAGE_HALF(lX, gX, r0g, h, t) do {                                     \
    int _buf = (t) & 1;                                                        \
    _Pragma("unroll")                                                          \
    for (int _i = 0; _i < 2; ++_i) {                                           \
        int _rl = (h) * 128 + (w * 2 + _i) * 8;                                \
        const short* _g = (gX) + (long)((r0g) + _rl + lr8) * 768               \
                               + (t) * 64 + scol;                              \
        __builtin_amdgcn_global_load_lds(                                      \
            (const __attribute__((address_space(1))) void*)_g,                 \
            (__attribute__((address_space(3))) void*)(&lX[_buf][_rl * 64]),    \
            16, 0, 0);                                                         \
    }                                                                          \
} while (0)

#define LOAD_A(mh, buf) do {                                                   \
    _Pragma("unroll")                                                          \
    for (int _t = 0; _t < 4; ++_t)                                             \
        _Pragma("unroll")                                                      \
        for (int _k = 0; _k < 2; ++_k)                                         \
            af[_t][_k] = *(const short8*)(&lA[buf][                            \
                (wm + (mh) * 64 + _t * 16 + fr) * 64 +                         \
                ((_k * 4 + kq + fr) & 7) * 8]);                                \
} while (0)

#define LOAD_B(nh, buf) do {                                                   \
    _Pragma("unroll")                                                          \
    for (int _t = 0; _t < 2; ++_t)                                             \
        _Pragma("unroll")                                                      \
        for (int _k = 0; _k < 2; ++_k)                                         \
            bq[(nh) * 2 + _t][_k] = *(const short8*)(&lB[buf][                 \
                (wn + (nh) * 32 + _t * 16 + fr) * 64 +                         \
                ((_k * 4 + kq + fr) & 7) * 8]);                                \
} while (0)

#define MMA_Q(mh, nh) do {                                                     \
    __builtin_amdgcn_s_setprio(1);                                             \
    _Pragma("unroll")                                                          \
    for (int _t = 0; _t < 4; ++_t)                                             \
        _Pragma("unroll")                                                      \
        for (int _n = 0; _n < 2; ++_n)                                         \
            _Pragma("unroll")                                                  \
            for (int _k = 0; _k < 2; ++_k)                                     \
                acc[(mh) * 4 + _t][(nh) * 2 + _n] =                            \
                    __builtin_amdgcn_mfma_f32_16x16x32_bf16(                   \
                        af[_t][_k], bq[(nh) * 2 + _n][_k],                     \
                        acc[(mh) * 4 + _t][(nh) * 2 + _n], 0, 0, 0);           \
    __builtin_amdgcn_s_setprio(0);                                             \
} while (0)

#define BAR() __builtin_amdgcn_s_barrier()
#define LGKM0() asm volatile("s_waitcnt lgkmcnt(0)" ::: "memory")
#define VMC4() asm volatile("s_waitcnt vmcnt(4)" ::: "memory")
#define VMC0() asm volatile("s_waitcnt vmcnt(0)" ::: "memory")

    // prologue: T0 {B0,B1,A0,A1}, T1 {B0,B1}; confirm T0
    STAGE_HALF(lB, B, n0, 0, 0);
    STAGE_HALF(lB, B, n0, 1, 0);
    STAGE_HALF(lA, A, m0, 0, 0);
    STAGE_HALF(lA, A, m0, 1, 0);
    STAGE_HALF(lB, B, n0, 0, 1);
    STAGE_HALF(lB, B, n0, 1, 1);
    VMC4();
    BAR();

    #pragma unroll 1
    for (int i = 0; i < 6; ++i) {
        const int t0 = 2 * i;
        const bool more = (i < 5);
        // phase 1
        LOAD_A(0, 0); LOAD_B(0, 0);
        STAGE_HALF(lA, A, m0, 0, t0 + 1);
        BAR(); LGKM0(); MMA_Q(0, 0); BAR();
        // phase 2
        LOAD_B(1, 0);
        STAGE_HALF(lA, A, m0, 1, t0 + 1);
        BAR(); LGKM0(); MMA_Q(0, 1); BAR();
        // phase 3
        LOAD_A(1, 0);
        if (more) STAGE_HALF(lB, B, n0, 0, t0 + 2);
        BAR(); LGKM0(); MMA_Q(1, 1); BAR();
        // phase 4: held regs; confirm tile 2i+1 after MFMA
        if (more) STAGE_HALF(lB, B, n0, 1, t0 + 2);
        BAR(); LGKM0(); MMA_Q(1, 0);
        if (more) { VMC4(); } else { VMC0(); }
        BAR();
        // phase 5
        LOAD_A(0, 1); LOAD_B(0, 1);
        if (more) STAGE_HALF(lA, A, m0, 0, t0 + 2);
        BAR(); LGKM0(); MMA_Q(0, 0); BAR();
        // phase 6
        LOAD_B(1, 1);
        if (more) STAGE_HALF(lA, A, m0, 1, t0 + 2);
        BAR(); LGKM0(); MMA_Q(0, 1); BAR();
        // phase 7
        LOAD_A(1, 1);
        if (more) STAGE_HALF(lB, B, n0, 0, t0 + 3);
        BAR(); LGKM0(); MMA_Q(1, 1); BAR();
        // phase 8: confirm tile 2i+2 after MFMA
        if (more) STAGE_HALF(lB, B, n0, 1, t0 + 3);
        BAR(); LGKM0(); MMA_Q(1, 0);
        if (more) VMC4();
        BAR();
    }

    // ---- epilogue; C/D layout: col = lane&15, row = (lane>>4)*4 + r
    const int type = (bx >= 6) ? 2 : (bx >= 3 ? 1 : 0);
    const int nl0 = n0 - type * 768;
    const int r0 = wm + (lane >> 4) * 4;
    const int c0 = wn + (lane & 15);
    if (type < 2) {
        short* dst = (type == 0) ? Q : Kb;
        const int par = lane & 1;
        #pragma unroll
        for (int tmi = 0; tmi < 8; ++tmi)
            #pragma unroll
            for (int tni = 0; tni < 4; ++tni) {
                int col = nl0 + c0 + tni * 16;
                const float2* rtc = rt + (col >> 1);
                #pragma unroll
                for (int r = 0; r < 4; ++r) {
                    int row = m0 + r0 + tmi * 16 + r;
                    float val = acc[tmi][tni][r];
                    float pv = __shfl_xor(val, 1);
                    float2 cs = rtc[(row & 255) * 384];
                    float re = par ? pv : val;
                    float im = par ? val : pv;
                    float o = par ? (re * cs.y + im * cs.x)
                                  : (re * cs.x - im * cs.y);
                    dst[(long)row * 768 + col] = f2bf(o);
                }
            }
    } else {
        #pragma unroll
        for (int tmi = 0; tmi < 8; ++tmi)
            #pragma unroll
            for (int tni = 0; tni < 4; ++tni) {
                int col = nl0 + c0 + tni * 16;
                #pragma unroll
                for (int r = 0; r < 4; ++r) {
                    int row = m0 + r0 + tmi * 16 + r;
                    Vt[((long)(row >> 8) * 768 + col) * 256 + (row & 255)] =
                        f2bf(acc[tmi][tni][r]);
                }
            }
    }
#undef STAGE_HALF
#undef LOAD_A
#undef LOAD_B
#undef MMA_Q
#undef BAR
#undef LGKM0
#undef VMC4
#undef VMC0
}

// ---------------------------------------------------------------------------
// Fully fused attention tail: S = q k^T * scale -> causal softmax -> out = P v
// One kernel, grid 256 (1 block/CU, XCD-paired so mh-halves share k,v via L2),
// 512 threads = 8 waves (2m x 4n).
// Phase 1 (QK): 128 q-rows x 256 k-cols, K=768, double-buffered staging.
// Phase 2: exact softmax (full row in registers), P written to LDS bf16 in the
//   rotation-swizzled fragment layout (phys slot = (t'/8 + row) & 7).
// Phase 3 (PV): out[128][768] in 6 d-chunks of 128; A = P from LDS (free),
//   B = vt tiles double-buffered; causal limit kcN = mh ? 4 : 2.
// LDS map (shorts): [0,16384) lA dbuf | [16384,49152) lB dbuf
//   P chunks [0,32768) alias QK bufs after QK done
//   [49152,65536) lV dbuf | [65536,67584) f32 reduction scratch. 132 KB.
__global__ __launch_bounds__(512)
void attn_fused(const short* __restrict__ Qm, const short* __restrict__ Km,
                const short* __restrict__ Vm, float* __restrict__ out,
                float scale) {
    int p = blockIdx.x;
    int c = p & 7, j = p >> 3;          // j in [0,32)
    int bz = c * 16 + (j >> 1);
    int mh = j & 1;
    const short* Ab = Qm + (long)bz * 196608 + (long)mh * 98304;
    const short* Bb = Km + (long)bz * 196608;
    const short* Vb = Vm + (long)bz * 196608;   // vt[batch][768 d][256 t]

    __shared__ short smem[67584];

    const int tid = threadIdx.x;
    const int w = tid >> 6, lane = tid & 63;
    const int wm = (w >> 2) * 64;       // 2 m-groups of 64 q-rows
    const int wn = (w & 3) * 64;        // 4 n-groups of 64 t-cols (QK)
    const int lr8 = lane >> 3;
    const int scol = (((lane & 7) - lr8) & 7) * 8;
    const int fr = lane & 15, kq = lane >> 4;
    const int cb = fr;

    f32x4 acc[4][4] = {};

#define GLL(g, l) __builtin_amdgcn_global_load_lds(                            \
        (const __attribute__((address_space(1))) void*)(g),                    \
        (__attribute__((address_space(3))) void*)(l), 16, 0, 0)

#define STAGE_QK(t) do { int _b = (t) & 1;                                     \
    _Pragma("unroll")                                                          \
    for (int _i = 0; _i < 2; ++_i) { int _s = _i * 8 + w;                      \
        GLL(Ab + (long)(_s * 8 + lr8) * 768 + (t) * 64 + scol,                 \
            smem + _b * 8192 + _s * 512); }                                    \
    _Pragma("unroll")                                                          \
    for (int _i = 0; _i < 4; ++_i) { int _s = _i * 8 + w;                      \
        GLL(Bb + (long)(_s * 8 + lr8) * 768 + (t) * 64 + scol,                 \
            smem + 16384 + _b * 16384 + _s * 512); } } while (0)

#define STAGE_V(dc, kc, b) do {                                                \
    _Pragma("unroll")                                                          \
    for (int _i = 0; _i < 2; ++_i) { int _s = _i * 8 + w;                      \
        GLL(Vb + (long)((dc) * 128 + _s * 8 + lr8) * 256 + (kc) * 64 + scol,   \
            smem + 49152 + (b) * 8192 + _s * 512); } } while (0)

    // ---- phase 1: QK, double-buffered ---------------------------------
    STAGE_QK(0);
    __syncthreads();
    #pragma unroll 1
    for (int t = 0; t < 12; ++t) {
        if (t < 11) STAGE_QK(t + 1);
        const short* la = smem + (t & 1) * 8192;
        const short* lb = smem + 16384 + (t & 1) * 16384;
        #pragma unroll
        for (int cc = 0; cc < 2; ++cc) {
            const int sphys = ((cc * 4 + kq + fr) & 7) * 8;
            short8 afr[4], bfr[4];
            #pragma unroll
            for (int tmi = 0; tmi < 4; ++tmi)
                afr[tmi] = *(const short8*)(la + (wm + fr + tmi * 16) * 64 + sphys);
            #pragma unroll
            for (int tni = 0; tni < 4; ++tni)
                bfr[tni] = *(const short8*)(lb + (wn + fr + tni * 16) * 64 + sphys);
            #pragma unroll
            for (int tmi = 0; tmi < 4; ++tmi)
                #pragma unroll
                for (int tni = 0; tni < 4; ++tni)
                    acc[tmi][tni] = __builtin_amdgcn_mfma_f32_16x16x32_bf16(
                        afr[tmi], bfr[tni], acc[tmi][tni], 0, 0, 0);
        }
        __syncthreads();
    }

    // V tile (0,0) fetch rides under the softmax
    STAGE_V(0, 0, 0);

    // ---- phase 2: exact causal softmax --------------------------------
    const int r0 = kq * 4;
    const int nw = w & 3;
    float* redm = (float*)(smem + 65536);
    float* reds = redm + 512;

    float M[16];
    #pragma unroll
    for (int tmi = 0; tmi < 4; ++tmi)
        #pragma unroll
        for (int r = 0; r < 4; ++r) {
            int rowL = wm + tmi * 16 + r0 + r;
            int tloc = mh * 128 + rowL;
            float m = -1e30f;
            #pragma unroll
            for (int tni = 0; tni < 4; ++tni) {
                int col = wn + cb + tni * 16;
                float v = (col <= tloc) ? acc[tmi][tni][r] * scale : -1e30f;
                acc[tmi][tni][r] = v;
                m = fmaxf(m, v);
            }
            m = fmaxf(m, __shfl_xor(m, 1));
            m = fmaxf(m, __shfl_xor(m, 2));
            m = fmaxf(m, __shfl_xor(m, 4));
            m = fmaxf(m, __shfl_xor(m, 8));
            M[tmi * 4 + r] = m;
        }
    if (cb == 0) {
        #pragma unroll
        for (int tmi = 0; tmi < 4; ++tmi)
            #pragma unroll
            for (int r = 0; r < 4; ++r)
                redm[(wm + tmi * 16 + r0 + r) * 4 + nw] = M[tmi * 4 + r];
    }
    __syncthreads();
    #pragma unroll
    for (int tmi = 0; tmi < 4; ++tmi)
        #pragma unroll
        for (int r = 0; r < 4; ++r) {
            f32x4 v = *(const f32x4*)(redm + (wm + tmi * 16 + r0 + r) * 4);
            M[tmi * 4 + r] = fmaxf(fmaxf(v.x, v.y), fmaxf(v.z, v.w));
        }
    float Sm[16];
    #pragma unroll
    for (int tmi = 0; tmi < 4; ++tmi)
        #pragma unroll
        for (int r = 0; r < 4; ++r) {
            float mm = M[tmi * 4 + r];
            float s = 0.f;
            #pragma unroll
            for (int tni = 0; tni < 4; ++tni) {
                float e = __expf(acc[tmi][tni][r] - mm);
                acc[tmi][tni][r] = e;
                s += e;
            }
            s += __shfl_xor(s, 1);
            s += __shfl_xor(s, 2);
            s += __shfl_xor(s, 4);
            s += __shfl_xor(s, 8);
            Sm[tmi * 4 + r] = s;
        }
    if (cb == 0) {
        #pragma unroll
        for (int tmi = 0; tmi < 4; ++tmi)
            #pragma unroll
            for (int r = 0; r < 4; ++r)
                reds[(wm + tmi * 16 + r0 + r) * 4 + nw] = Sm[tmi * 4 + r];
    }
    __syncthreads();

    // normalize + write P into LDS (bf16, rotation-swizzled fragment layout)
    // This wave owns t-chunk (w&3): t = wn + cb + tni*16; in-chunk t' = cb+tni*16
    short* Pch = smem + (w & 3) * 8192;
    #pragma unroll
    for (int tmi = 0; tmi < 4; ++tmi)
        #pragma unroll
        for (int r = 0; r < 4; ++r) {
            int rowL = wm + tmi * 16 + r0 + r;
            f32x4 sv = *(const f32x4*)(reds + rowL * 4);
            float inv = 1.0f / (sv.x + sv.y + sv.z + sv.w);
            #pragma unroll
            for (int tni = 0; tni < 4; ++tni) {
                int l = (cb >> 3) + tni * 2;            // logical 8-short slot
                Pch[rowL * 64 + ((l + rowL) & 7) * 8 + (cb & 7)] =
                    f2bf(acc[tmi][tni][r] * inv);
            }
        }
    __syncthreads();   // P visible; V tile (0,0) complete (vmcnt drained)

    // ---- phase 3: PV, double-buffered V -------------------------------
    const int kcN = mh ? 4 : 2;          // causal t-extent: chunks of 64
    const int wn2 = (w & 3) * 32;        // 4 n-groups of 32 d-cols
    const long rowB = (long)bz * 256 + (long)mh * 128;
    int vb = 0;
    #pragma unroll 1
    for (int dc = 0; dc < 6; ++dc) {
        f32x4 a2[4][2] = {};
        #pragma unroll 1
        for (int kc = 0; kc < kcN; ++kc) {
            int ndc = dc, nkc = kc + 1;
            if (nkc == kcN) { ndc = dc + 1; nkc = 0; }
            if (ndc < 6) STAGE_V(ndc, nkc, vb ^ 1);
            const short* pch = smem + kc * 8192;
            const short* lv = smem + 49152 + vb * 8192;
            #pragma unroll
            for (int cc = 0; cc < 2; ++cc) {
                const int sp = ((cc * 4 + kq + fr) & 7) * 8;
                short8 ap[4], bv[2];
                #pragma unroll
                for (int tmi = 0; tmi < 4; ++tmi)
                    ap[tmi] = *(const short8*)(pch + (wm + tmi * 16 + fr) * 64 + sp);
                #pragma unroll
                for (int tn = 0; tn < 2; ++tn)
                    bv[tn] = *(const short8*)(lv + (wn2 + tn * 16 + fr) * 64 + sp);
                #pragma unroll
                for (int tmi = 0; tmi < 4; ++tmi)
                    #pragma unroll
                    for (int tn = 0; tn < 2; ++tn)
                        a2[tmi][tn] = __builtin_amdgcn_mfma_f32_16x16x32_bf16(
                            ap[tmi], bv[tn], a2[tmi][tn], 0, 0, 0);
            }
            __syncthreads();
            vb ^= 1;
        }
        // store out chunk [128 q][128 d], fp32
        #pragma unroll
        for (int tmi = 0; tmi < 4; ++tmi)
            #pragma unroll
            for (int tn = 0; tn < 2; ++tn)
                #pragma unroll
                for (int r = 0; r < 4; ++r) {
                    long row = rowB + wm + tmi * 16 + kq * 4 + r;
                    int col = dc * 128 + wn2 + tn * 16 + cb;
                    out[row * 768 + col] = a2[tmi][tn][r];
                }
    }
#undef GLL
#undef STAGE_QK
#undef STAGE_V
}

// ---------------------------------------------------------------------------
extern "C" void kernel_launch(void* const* d_in, const int* in_sizes, int n_in,
                              void* d_out, int out_size, void* d_ws, size_t ws_size,
                              hipStream_t stream) {
    const float* x  = (const float*)d_in[0];
    const float* Wq = (const float*)d_in[1];
    const float* Wk = (const float*)d_in[2];
    const float* Wv = (const float*)d_in[3];

    char* ws = (char*)d_ws;
    short*  xb = (short*)(ws);                   // 48 MB   x bf16
    short*  wt = (short*)(ws + 50331648);        // 3.375MB Wqkv^T bf16 [2304,768]
    short*  qb = (short*)(ws + 53870592);        // 48 MB   q bf16 (roped)
    short*  kb = (short*)(ws + 104202240);       // 48 MB   k bf16 (roped)
    short*  vt = (short*)(ws + 154533888);       // 48 MB   v^T bf16 [128][768][256]
    float2* rt = (float2*)(ws + 255197184);      // 768 KB  rope table

    cvt_x<<<24576, 256, 0, stream>>>(x, xb);
    dim3 gw(24, 24);
    cvt_wt<<<gw, 256, 0, stream>>>(Wq, wt);
    cvt_wt<<<gw, 256, 0, stream>>>(Wk, wt + 589824);
    cvt_wt<<<gw, 256, 0, stream>>>(Wv, wt + 1179648);
    rope_tab<<<384, 256, 0, stream>>>(rt);

    // Fused QKV: [32768,768] x [2304,768]^T, 256^2 8-phase, RoPE/v-T epilogue
    qkv256<<<1152, 512, 0, stream>>>(xb, wt, qb, kb, vt, rt);

    // Fused attention tail: QK^T -> softmax -> PV, one kernel
    attn_fused<<<256, 512, 0, stream>>>(qb, kb, vt, (float*)d_out,
                                        0.0360843918f);
}

// Round 4
// 388.301 us; speedup vs baseline: 1.1362x; 1.0035x over previous
//
#include <hip/hip_runtime.h>
#include <hip/hip_bf16.h>
#include <stdint.h>

// B=128, T=256, C=768, D=768. M_total = 32768.

typedef __attribute__((ext_vector_type(8))) short short8;   // 8 x bf16 (4 VGPRs)
typedef __attribute__((ext_vector_type(4))) short short4v;  // 4 x bf16 (8B)
typedef __attribute__((ext_vector_type(4))) float f32x4;

__device__ __forceinline__ short f2bf(float f) {
    uint32_t u = __float_as_uint(f);
    u += 0x7fffu + ((u >> 16) & 1u);   // RNE
    return (short)(u >> 16);
}

// ---------------------------------------------------------------------------
__global__ __launch_bounds__(256) void cvt_x(const float* __restrict__ x,
                                             short* __restrict__ xb) {
    long i = ((long)blockIdx.x * 256 + threadIdx.x) * 4;
    f32x4 v = *(const f32x4*)(x + i);
    short4v o;
    o.x = f2bf(v.x); o.y = f2bf(v.y); o.z = f2bf(v.z); o.w = f2bf(v.w);
    *(short4v*)(xb + i) = o;
}

// W [768,768] fp32 -> Wt [768,768] bf16 transposed
__global__ __launch_bounds__(256) void cvt_wt(const float* __restrict__ W,
                                              short* __restrict__ Wt) {
    __shared__ float tile[32][33];
    int d0 = blockIdx.x * 32, c0 = blockIdx.y * 32;
    int tr = threadIdx.x >> 5, tc = threadIdx.x & 31;
    #pragma unroll
    for (int i = 0; i < 32; i += 8)
        tile[tr + i][tc] = W[(long)(c0 + tr + i) * 768 + d0 + tc];
    __syncthreads();
    #pragma unroll
    for (int i = 0; i < 32; i += 8)
        Wt[(long)(d0 + tr + i) * 768 + c0 + tc] = f2bf(tile[tc][tr + i]);
}

// RoPE table: rt[t*384 + j] = (cos, sin)
__global__ __launch_bounds__(256) void rope_tab(float2* __restrict__ rt) {
    int i = blockIdx.x * 256 + threadIdx.x;   // 98304
    int t = i / 384, j = i - t * 384;
    const float CE = -0.034603417655f;        // -2*log2(10000)/768
    float th = exp2f((float)j * CE);
    float s, c;
    sincosf((float)t * th, &s, &c);
    rt[i] = make_float2(c, s);
}

// ---------------------------------------------------------------------------
// Fused QKV GEMM: 256x256 tile, BK=64, 8 waves (2Mx4N), 8-phase schedule with
// counted vmcnt (T3+T4), setprio around MFMA clusters (T5), rotation LDS
// swizzle (0 bank conflicts).
// C = A[32768x768] * B[2304x768]^T; epilogue: RoPE (q,k), transpose (v).
__global__ __launch_bounds__(512, 2)
void qkv256(const short* __restrict__ A, const short* __restrict__ B,
            short* __restrict__ Q, short* __restrict__ Kb,
            short* __restrict__ Vt, const float2* __restrict__ rt) {
    // grid 1152 flat = 8 XCDs x 16 M-stripes x 9 N-blocks (bijective)
    int p = blockIdx.x;
    int c = p & 7, j = p >> 3;          // j in [0,144)
    int st = j / 9;
    int bx = j - st * 9;                // [0,9)
    int by = c * 16 + st;               // [0,128)
    const int m0 = by * 256, n0 = bx * 256;

    __shared__ short lA[2][256 * 64];   // 64 KB
    __shared__ short lB[2][256 * 64];   // 64 KB

    const int tid = threadIdx.x;
    const int w = tid >> 6, lane = tid & 63;
    const int wm = (w >> 2) * 128;      // 2 M-waves
    const int wn = (w & 3) * 64;        // 4 N-waves
    const int lr8 = lane >> 3;
    const int scol = (((lane & 7) - lr8) & 7) * 8;  // rotation swizzle (stage)
    const int fr = lane & 15, kq = lane >> 4;

    f32x4 acc[8][4] = {};
    short8 af[4][2];
    short8 bq[4][2];

#define STAGE_HALF(lX, gX, r0g, h, t) do {                                     \
    int _buf = (t) & 1;                                                        \
    _Pragma("unroll")                                                          \
    for (int _i = 0; _i < 2; ++_i) {                                           \
        int _rl = (h) * 128 + (w * 2 + _i) * 8;                                \
        const short* _g = (gX) + (long)((r0g) + _rl + lr8) * 768               \
                               + (t) * 64 + scol;                              \
        __builtin_amdgcn_global_load_lds(                                      \
            (const __attribute__((address_space(1))) void*)_g,                 \
            (__attribute__((address_space(3))) void*)(&lX[_buf][_rl * 64]),    \
            16, 0, 0);                                                         \
    }                                                                          \
} while (0)

#define LOAD_A(mh, buf) do {                                                   \
    _Pragma("unroll")                                                          \
    for (int _t = 0; _t < 4; ++_t)                                             \
        _Pragma("unroll")                                                      \
        for (int _k = 0; _k < 2; ++_k)                                         \
            af[_t][_k] = *(const short8*)(&lA[buf][                            \
                (wm + (mh) * 64 + _t * 16 + fr) * 64 +                         \
                ((_k * 4 + kq + fr) & 7) * 8]);                                \
} while (0)

#define LOAD_B(nh, buf) do {                                                   \
    _Pragma("unroll")                                                          \
    for (int _t = 0; _t < 2; ++_t)                                             \
        _Pragma("unroll")                                                      \
        for (int _k = 0; _k < 2; ++_k)                                         \
            bq[(nh) * 2 + _t][_k] = *(const short8*)(&lB[buf][                 \
                (wn + (nh) * 32 + _t * 16 + fr) * 64 +                         \
                ((_k * 4 + kq + fr) & 7) * 8]);                                \
} while (0)

#define MMA_Q(mh, nh) do {                                                     \
    __builtin_amdgcn_s_setprio(1);                                             \
    _Pragma("unroll")                                                          \
    for (int _t = 0; _t < 4; ++_t)                                             \
        _Pragma("unroll")                                                      \
        for (int _n = 0; _n < 2; ++_n)                                         \
            _Pragma("unroll")                                                  \
            for (int _k = 0; _k < 2; ++_k)                                     \
                acc[(mh) * 4 + _t][(nh) * 2 + _n] =                            \
                    __builtin_amdgcn_mfma_f32_16x16x32_bf16(                   \
                        af[_t][_k], bq[(nh) * 2 + _n][_k],                     \
                        acc[(mh) * 4 + _t][(nh) * 2 + _n], 0, 0, 0);           \
    __builtin_amdgcn_s_setprio(0);                                             \
} while (0)

#define BAR() __builtin_amdgcn_s_barrier()
#define LGKM0() asm volatile("s_waitcnt lgkmcnt(0)" ::: "memory")
#define VMC4() asm volatile("s_waitcnt vmcnt(4)" ::: "memory")
#define VMC0() asm volatile("s_waitcnt vmcnt(0)" ::: "memory")

    // prologue: T0 {B0,B1,A0,A1}, T1 {B0,B1}; confirm T0
    STAGE_HALF(lB, B, n0, 0, 0);
    STAGE_HALF(lB, B, n0, 1, 0);
    STAGE_HALF(lA, A, m0, 0, 0);
    STAGE_HALF(lA, A, m0, 1, 0);
    STAGE_HALF(lB, B, n0, 0, 1);
    STAGE_HALF(lB, B, n0, 1, 1);
    VMC4();
    BAR();

    #pragma unroll 1
    for (int i = 0; i < 6; ++i) {
        const int t0 = 2 * i;
        const bool more = (i < 5);
        // phase 1
        LOAD_A(0, 0); LOAD_B(0, 0);
        STAGE_HALF(lA, A, m0, 0, t0 + 1);
        BAR(); LGKM0(); MMA_Q(0, 0); BAR();
        // phase 2
        LOAD_B(1, 0);
        STAGE_HALF(lA, A, m0, 1, t0 + 1);
        BAR(); LGKM0(); MMA_Q(0, 1); BAR();
        // phase 3
        LOAD_A(1, 0);
        if (more) STAGE_HALF(lB, B, n0, 0, t0 + 2);
        BAR(); LGKM0(); MMA_Q(1, 1); BAR();
        // phase 4: held regs; confirm tile 2i+1 after MFMA
        if (more) STAGE_HALF(lB, B, n0, 1, t0 + 2);
        BAR(); LGKM0(); MMA_Q(1, 0);
        if (more) { VMC4(); } else { VMC0(); }
        BAR();
        // phase 5
        LOAD_A(0, 1); LOAD_B(0, 1);
        if (more) STAGE_HALF(lA, A, m0, 0, t0 + 2);
        BAR(); LGKM0(); MMA_Q(0, 0); BAR();
        // phase 6
        LOAD_B(1, 1);
        if (more) STAGE_HALF(lA, A, m0, 1, t0 + 2);
        BAR(); LGKM0(); MMA_Q(0, 1); BAR();
        // phase 7
        LOAD_A(1, 1);
        if (more) STAGE_HALF(lB, B, n0, 0, t0 + 3);
        BAR(); LGKM0(); MMA_Q(1, 1); BAR();
        // phase 8: confirm tile 2i+2 after MFMA
        if (more) STAGE_HALF(lB, B, n0, 1, t0 + 3);
        BAR(); LGKM0(); MMA_Q(1, 0);
        if (more) VMC4();
        BAR();
    }

    // ---- epilogue; C/D layout: col = lane&15, row = (lane>>4)*4 + r
    const int type = (bx >= 6) ? 2 : (bx >= 3 ? 1 : 0);
    const int nl0 = n0 - type * 768;
    const int r0 = wm + (lane >> 4) * 4;
    const int c0 = wn + (lane & 15);
    if (type < 2) {
        short* dst = (type == 0) ? Q : Kb;
        const int par = lane & 1;
        #pragma unroll
        for (int tmi = 0; tmi < 8; ++tmi)
            #pragma unroll
            for (int tni = 0; tni < 4; ++tni) {
                int col = nl0 + c0 + tni * 16;
                const float2* rtc = rt + (col >> 1);
                #pragma unroll
                for (int r = 0; r < 4; ++r) {
                    int row = m0 + r0 + tmi * 16 + r;
                    float val = acc[tmi][tni][r];
                    float pv = __shfl_xor(val, 1);
                    float2 cs = rtc[(row & 255) * 384];
                    float re = par ? pv : val;
                    float im = par ? val : pv;
                    float o = par ? (re * cs.y + im * cs.x)
                                  : (re * cs.x - im * cs.y);
                    dst[(long)row * 768 + col] = f2bf(o);
                }
            }
    } else {
        #pragma unroll
        for (int tmi = 0; tmi < 8; ++tmi)
            #pragma unroll
            for (int tni = 0; tni < 4; ++tni) {
                int col = nl0 + c0 + tni * 16;
                #pragma unroll
                for (int r = 0; r < 4; ++r) {
                    int row = m0 + r0 + tmi * 16 + r;
                    Vt[((long)(row >> 8) * 768 + col) * 256 + (row & 255)] =
                        f2bf(acc[tmi][tni][r]);
                }
            }
    }
#undef STAGE_HALF
#undef LOAD_A
#undef LOAD_B
#undef MMA_Q
#undef BAR
#undef LGKM0
#undef VMC4
#undef VMC0
}

// ---------------------------------------------------------------------------
// Fused attention tail v2: grid 512 = (batch, q-quarter), 256 threads (4
// waves), LDS exactly 80 KB -> 2 blocks/CU (barrier drains in one block
// overlap compute in the other). Causal trimming: block qh only stages and
// computes k-cols t < (qh+1)*64. Heavy/light blocks paired per CU via the
// qh <-> 3-qh flip on the high batch bit. Per-batch blocks are XCD-colocated.
// LDS (shorts): lA dbuf [0,8192) | lB dbuf [8192,40960) (NC<=4 chunks)
//   after QK, aliased: P [0,16384) | V dbuf [16384,32768) | f32 scratch
//   at [32768,33792). Total 81920 B.
__global__ __launch_bounds__(256)
void attn2(const short* __restrict__ Qm, const short* __restrict__ Km,
           const short* __restrict__ Vm, float* __restrict__ out,
           float scale) {
    int p = blockIdx.x;
    int c = p & 7, j = p >> 3;          // j in [0,64)
    int b = j >> 2, q0 = j & 3;
    int qh = (b & 8) ? 3 - q0 : q0;     // heavy/light pairing across CU rounds
    int bz = c * 16 + b;
    const int NC = qh + 1;              // causal t-extent in 64-chunks
    const short* Ab = Qm + (long)bz * 196608 + (long)qh * 49152;  // 64 q-rows
    const short* Bb = Km + (long)bz * 196608;
    const short* Vb = Vm + (long)bz * 196608;   // vt[batch][768 d][256 t]

    __shared__ short smem[40960];       // 80 KB

    const int tid = threadIdx.x;
    const int w = tid >> 6, lane = tid & 63;
    const int lr8 = lane >> 3;
    const int scol = (((lane & 7) - lr8) & 7) * 8;  // rotation swizzle
    const int fr = lane & 15, kq = lane >> 4;

    f32x4 acc[4][4] = {};

#define GLL(g, l) __builtin_amdgcn_global_load_lds(                            \
        (const __attribute__((address_space(1))) void*)(g),                    \
        (__attribute__((address_space(3))) void*)(l), 16, 0, 0)

    // ---- phase 1: QK (64 q-rows x NC*64 t-cols), double-buffered ------
    // lA buf: 4096 shorts; lB buf: 16384 shorts (max NC=4)
#define STAGE_QK(t) do { int _b = (t) & 1;                                     \
    _Pragma("unroll")                                                          \
    for (int _i = 0; _i < 2; ++_i) { int _s = _i * 4 + w;                      \
        GLL(Ab + (long)(_s * 8 + lr8) * 768 + (t) * 64 + scol,                 \
            smem + _b * 4096 + _s * 512); }                                    \
    for (int _i = 0; _i < 2 * NC; ++_i) { int _s = _i * 4 + w;                 \
        GLL(Bb + (long)(_s * 8 + lr8) * 768 + (t) * 64 + scol,                 \
            smem + 8192 + _b * 16384 + _s * 512); } } while (0)

#define STAGE_V(dc, kc, vb) do {                                               \
    _Pragma("unroll")                                                          \
    for (int _i = 0; _i < 4; ++_i) { int _s = _i * 4 + w;                      \
        GLL(Vb + (long)((dc) * 128 + _s * 8 + lr8) * 256 + (kc) * 64 + scol,   \
            smem + 16384 + (vb) * 8192 + _s * 512); } } while (0)

    STAGE_QK(0);
    __syncthreads();
    #pragma unroll 1
    for (int t = 0; t < 12; ++t) {
        if (t < 11) STAGE_QK(t + 1);
        if (w < NC) {
            const short* la = smem + (t & 1) * 4096;
            const short* lb = smem + 8192 + (t & 1) * 16384 + w * 4096;
            #pragma unroll
            for (int cc = 0; cc < 2; ++cc) {
                const int sp = ((cc * 4 + kq + fr) & 7) * 8;
                short8 afr[4], bfr[4];
                #pragma unroll
                for (int tmi = 0; tmi < 4; ++tmi)
                    afr[tmi] = *(const short8*)(la + (tmi * 16 + fr) * 64 + sp);
                #pragma unroll
                for (int tni = 0; tni < 4; ++tni)
                    bfr[tni] = *(const short8*)(lb + (tni * 16 + fr) * 64 + sp);
                #pragma unroll
                for (int tmi = 0; tmi < 4; ++tmi)
                    #pragma unroll
                    for (int tni = 0; tni < 4; ++tni)
                        acc[tmi][tni] = __builtin_amdgcn_mfma_f32_16x16x32_bf16(
                            afr[tmi], bfr[tni], acc[tmi][tni], 0, 0, 0);
            }
        }
        __syncthreads();
    }

    // V tile (0,0) fetch rides under the softmax
    STAGE_V(0, 0, 0);

    // ---- phase 2: exact causal softmax (rows 0..63 local) -------------
    const int r0 = kq * 4;
    float* redm = (float*)(smem + 32768);   // [64][4]
    float* reds = redm + 256;               // [64][4]

    float M[16];
    #pragma unroll
    for (int tmi = 0; tmi < 4; ++tmi)
        #pragma unroll
        for (int r = 0; r < 4; ++r) {
            int rowL = tmi * 16 + r0 + r;
            int tloc = qh * 64 + rowL;
            float m = -1e30f;
            #pragma unroll
            for (int tni = 0; tni < 4; ++tni) {
                int col = w * 64 + fr + tni * 16;
                float v = (col <= tloc) ? acc[tmi][tni][r] * scale : -1e30f;
                acc[tmi][tni][r] = v;
                m = fmaxf(m, v);
            }
            m = fmaxf(m, __shfl_xor(m, 1));
            m = fmaxf(m, __shfl_xor(m, 2));
            m = fmaxf(m, __shfl_xor(m, 4));
            m = fmaxf(m, __shfl_xor(m, 8));
            M[tmi * 4 + r] = m;
        }
    if (fr == 0) {
        #pragma unroll
        for (int tmi = 0; tmi < 4; ++tmi)
            #pragma unroll
            for (int r = 0; r < 4; ++r)
                redm[(tmi * 16 + r0 + r) * 4 + w] = M[tmi * 4 + r];
    }
    __syncthreads();
    #pragma unroll
    for (int tmi = 0; tmi < 4; ++tmi)
        #pragma unroll
        for (int r = 0; r < 4; ++r) {
            f32x4 v = *(const f32x4*)(redm + (tmi * 16 + r0 + r) * 4);
            M[tmi * 4 + r] = fmaxf(fmaxf(v.x, v.y), fmaxf(v.z, v.w));
        }
    float Sm[16];
    #pragma unroll
    for (int tmi = 0; tmi < 4; ++tmi)
        #pragma unroll
        for (int r = 0; r < 4; ++r) {
            float mm = M[tmi * 4 + r];
            float s = 0.f;
            #pragma unroll
            for (int tni = 0; tni < 4; ++tni) {
                float e = __expf(acc[tmi][tni][r] - mm);
                acc[tmi][tni][r] = e;
                s += e;
            }
            s += __shfl_xor(s, 1);
            s += __shfl_xor(s, 2);
            s += __shfl_xor(s, 4);
            s += __shfl_xor(s, 8);
            Sm[tmi * 4 + r] = s;
        }
    if (fr == 0) {
        #pragma unroll
        for (int tmi = 0; tmi < 4; ++tmi)
            #pragma unroll
            for (int r = 0; r < 4; ++r)
                reds[(tmi * 16 + r0 + r) * 4 + w] = Sm[tmi * 4 + r];
    }
    __syncthreads();

    // normalize + write P into LDS (bf16, rotation-swizzled fragment layout)
    // wave w owns t-chunk w: in-chunk t' = fr + tni*16
    short* Pch = smem + w * 4096;
    #pragma unroll
    for (int tmi = 0; tmi < 4; ++tmi)
        #pragma unroll
        for (int r = 0; r < 4; ++r) {
            int rowL = tmi * 16 + r0 + r;
            f32x4 sv = *(const f32x4*)(reds + rowL * 4);
            float inv = 1.0f / (sv.x + sv.y + sv.z + sv.w);
            #pragma unroll
            for (int tni = 0; tni < 4; ++tni) {
                int l = (fr >> 3) + tni * 2;           // logical 8-short slot
                Pch[rowL * 64 + ((l + rowL) & 7) * 8 + (fr & 7)] =
                    f2bf(acc[tmi][tni][r] * inv);
            }
        }
    __syncthreads();   // P visible; V tile (0,0) complete (vmcnt drained)

    // ---- phase 3: PV, double-buffered V -------------------------------
    const int wn2 = w * 32;              // 4 n-groups of 32 d-cols
    const long rowB = (long)bz * 256 + (long)qh * 64;
    int vb = 0;
    #pragma unroll 1
    for (int dc = 0; dc < 6; ++dc) {
        f32x4 a2[4][2] = {};
        #pragma unroll 1
        for (int kc = 0; kc < NC; ++kc) {
            int ndc = dc, nkc = kc + 1;
            if (nkc == NC) { ndc = dc + 1; nkc = 0; }
            if (ndc < 6) STAGE_V(ndc, nkc, vb ^ 1);
            const short* pch = smem + kc * 4096;
            const short* lv = smem + 16384 + vb * 8192;
            #pragma unroll
            for (int cc = 0; cc < 2; ++cc) {
                const int sp = ((cc * 4 + kq + fr) & 7) * 8;
                short8 ap[4], bv[2];
                #pragma unroll
                for (int tmi = 0; tmi < 4; ++tmi)
                    ap[tmi] = *(const short8*)(pch + (tmi * 16 + fr) * 64 + sp);
                #pragma unroll
                for (int tn = 0; tn < 2; ++tn)
                    bv[tn] = *(const short8*)(lv + (wn2 + tn * 16 + fr) * 64 + sp);
                #pragma unroll
                for (int tmi = 0; tmi < 4; ++tmi)
                    #pragma unroll
                    for (int tn = 0; tn < 2; ++tn)
                        a2[tmi][tn] = __builtin_amdgcn_mfma_f32_16x16x32_bf16(
                            ap[tmi], bv[tn], a2[tmi][tn], 0, 0, 0);
            }
            __syncthreads();
            vb ^= 1;
        }
        // store out chunk [64 q][128 d], fp32
        #pragma unroll
        for (int tmi = 0; tmi < 4; ++tmi)
            #pragma unroll
            for (int tn = 0; tn < 2; ++tn)
                #pragma unroll
                for (int r = 0; r < 4; ++r) {
                    long row = rowB + tmi * 16 + kq * 4 + r;
                    int col = dc * 128 + wn2 + tn * 16 + fr;
                    out[row * 768 + col] = a2[tmi][tn][r];
                }
    }
#undef GLL
#undef STAGE_QK
#undef STAGE_V
}

// ---------------------------------------------------------------------------
extern "C" void kernel_launch(void* const* d_in, const int* in_sizes, int n_in,
                              void* d_out, int out_size, void* d_ws, size_t ws_size,
                              hipStream_t stream) {
    const float* x  = (const float*)d_in[0];
    const float* Wq = (const float*)d_in[1];
    const float* Wk = (const float*)d_in[2];
    const float* Wv = (const float*)d_in[3];

    char* ws = (char*)d_ws;
    short*  xb = (short*)(ws);                   // 48 MB   x bf16
    short*  wt = (short*)(ws + 50331648);        // 3.375MB Wqkv^T bf16 [2304,768]
    short*  qb = (short*)(ws + 53870592);        // 48 MB   q bf16 (roped)
    short*  kb = (short*)(ws + 104202240);       // 48 MB   k bf16 (roped)
    short*  vt = (short*)(ws + 154533888);       // 48 MB   v^T bf16 [128][768][256]
    float2* rt = (float2*)(ws + 255197184);      // 768 KB  rope table

    cvt_x<<<24576, 256, 0, stream>>>(x, xb);
    dim3 gw(24, 24);
    cvt_wt<<<gw, 256, 0, stream>>>(Wq, wt);
    cvt_wt<<<gw, 256, 0, stream>>>(Wk, wt + 589824);
    cvt_wt<<<gw, 256, 0, stream>>>(Wv, wt + 1179648);
    rope_tab<<<384, 256, 0, stream>>>(rt);

    // Fused QKV: [32768,768] x [2304,768]^T, 256^2 8-phase, RoPE/v-T epilogue
    qkv256<<<1152, 512, 0, stream>>>(xb, wt, qb, kb, vt, rt);

    // Fused attention tail v2: 512 blocks (batch x q-quarter), 2 blocks/CU
    attn2<<<512, 256, 0, stream>>>(qb, kb, vt, (float*)d_out, 0.0360843918f);
}